// Round 4
// baseline (5695.802 us; speedup 1.0000x reference)
//
#include <hip/hip_runtime.h>
#include <math.h>

#define VOCAB 8000
#define EMB   512
#define HID   1024
#define SEQ_L 1024
#define G3    (3*HID)
#define NWG   64          // recurrence blocks
#define NWORK 192         // worker blocks
#define NITEM 289         // 24 gi_enc singles + 42 gi_enc quads + 48 gi_dec quads + 112 score quads + 63 score singles
#define JB    16          // h elements owned per recurrence block
#define POISON 0xAAAAAAAAu

typedef float v2f __attribute__((ext_vector_type(2)));

// worker-side poll (backoff; not on recurrence critical path)
__device__ __forceinline__ float pollf_relax(const float* p) {
  float v = __hip_atomic_load((float*)p, __ATOMIC_RELAXED, __HIP_MEMORY_SCOPE_AGENT);
  while (__float_as_uint(v) == POISON) {
    __builtin_amdgcn_s_sleep(1);
    v = __hip_atomic_load((float*)p, __ATOMIC_RELAXED, __HIP_MEMORY_SCOPE_AGENT);
  }
  return v;
}
// publish with anti-poison squash (atomicExch lands at Infinity Cache)
__device__ __forceinline__ void publishf(float* p, float v) {
  if (__float_as_uint(v) == POISON) v = __uint_as_float(POISON ^ 1u);
  atomicExch(p, v);
}
// sum over each 16-lane row, all in VALU via DPP (no LDS pipe)
__device__ __forceinline__ float row16_sum(float x) {
  int v = __float_as_int(x);
  x += __int_as_float(__builtin_amdgcn_update_dpp(0, v, 0xB1,  0xF, 0xF, false)); v = __float_as_int(x); // quad_perm [1,0,3,2]
  x += __int_as_float(__builtin_amdgcn_update_dpp(0, v, 0x4E,  0xF, 0xF, false)); v = __float_as_int(x); // quad_perm [2,3,0,1]
  x += __int_as_float(__builtin_amdgcn_update_dpp(0, v, 0x141, 0xF, 0xF, false)); v = __float_as_int(x); // row_half_mirror
  x += __int_as_float(__builtin_amdgcn_update_dpp(0, v, 0x140, 0xF, 0xF, false));                        // row_mirror
  return x;
}

// ---------------- prep: dec_in + valid mask ----------------
__global__ __launch_bounds__(1024) void prep_kernel(
    const int* __restrict__ target, const int* __restrict__ sos_p,
    const int* __restrict__ eos_p, int* __restrict__ dec_in,
    float* __restrict__ valid)
{
  int t = threadIdx.x;
  int eos = eos_p[0];
  dec_in[t] = (t == 0) ? sos_p[0] : target[t - 1];
  bool ne = (target[t] != eos);
  unsigned long long b = __ballot(ne);
  int lane = t & 63, w = t >> 6;
  __shared__ unsigned long long wb[16];
  if (lane == 0) wb[w] = b;
  __syncthreads();
  bool ok = (((~b) & ((1ull << lane) - 1ull)) == 0ull);
  for (int i = 0; i < 16; i++)
    if (i < w) ok = ok && (wb[i] == ~0ull);
  valid[t] = ok ? 1.0f : 0.0f;
}

// ---------------- 256-thread 128x128 fp32 NT GEMM sub-tile -----------------
// AMODE 0: plain A load (optional row gather idx). AMODE 1: atomic poison-poll A (hdec).
// CMODE 0: C via atomicExch + squash (IC-visible for concurrent consumers).
// CMODE 1: plain C store, x rowscale[m].
// All 1024 threads of the block must call with same K (lockstep __syncthreads).
template<int AMODE, int CMODE>
__device__ void gemm_tile(const float* __restrict__ A, const int* __restrict__ idx,
                          const float* __restrict__ B, const float* __restrict__ bias,
                          const float* __restrict__ rowscale, float* __restrict__ C,
                          int N, int K, int bm, int bn, bool active,
                          float (*As)[132], float (*Bs)[132], int stid)
{
  if (!active) {           // barrier-matched idle sub
    for (int t = 0, e = 2 * (K / 16); t < e; t++) __syncthreads();
    return;
  }
  const int tx = stid & 15, ty = stid >> 4;
  float acc[8][8];
#pragma unroll
  for (int i = 0; i < 8; i++)
#pragma unroll
    for (int jj = 0; jj < 8; jj++) acc[i][jj] = 0.f;

  for (int k0 = 0; k0 < K; k0 += 16) {
    __syncthreads();
#pragma unroll
    for (int r = 0; r < 2; r++) {
      int v = stid + 256 * r;
      int row = v >> 2;
      int kq = (v & 3) << 2;
      int m = bm + row;
      float4 av;
      if (AMODE == 0) {
        const float* ab = A + (size_t)(idx ? idx[m] : m) * K + k0 + kq;
        av = *(const float4*)ab;
      } else {
        const float* ab = A + (size_t)m * K + k0 + kq;
        av.x = pollf_relax(ab + 0); av.y = pollf_relax(ab + 1);
        av.z = pollf_relax(ab + 2); av.w = pollf_relax(ab + 3);
      }
      As[kq + 0][row] = av.x; As[kq + 1][row] = av.y;
      As[kq + 2][row] = av.z; As[kq + 3][row] = av.w;
      int n = bn + row;
      float4 bv = make_float4(0.f, 0.f, 0.f, 0.f);
      if (n < N) bv = *(const float4*)(B + (size_t)n * K + k0 + kq);
      Bs[kq + 0][row] = bv.x; Bs[kq + 1][row] = bv.y;
      Bs[kq + 2][row] = bv.z; Bs[kq + 3][row] = bv.w;
    }
    __syncthreads();
#pragma unroll
    for (int k = 0; k < 16; k++) {
      float am[8], bb[8];
      *(float4*)&am[0] = *(const float4*)&As[k][ty * 8];
      *(float4*)&am[4] = *(const float4*)&As[k][ty * 8 + 4];
      *(float4*)&bb[0] = *(const float4*)&Bs[k][tx * 8];
      *(float4*)&bb[4] = *(const float4*)&Bs[k][tx * 8 + 4];
#pragma unroll
      for (int i = 0; i < 8; i++)
#pragma unroll
        for (int jj = 0; jj < 8; jj++)
          acc[i][jj] += am[i] * bb[jj];
    }
  }
#pragma unroll
  for (int i = 0; i < 8; i++) {
    int m = bm + ty * 8 + i;
#pragma unroll
    for (int jj = 0; jj < 8; jj++) {
      int n = bn + tx * 8 + jj;
      if (n < N) {
        float vv = acc[i][jj] + bias[n];
        if (CMODE == 0) publishf(&C[(size_t)m * N + n], vv);
        else            C[(size_t)m * N + n] = vv * rowscale[m];
      }
    }
  }
}

// ---------------- fused persistent kernel -----------------------------------
// Blocks 0..63: GRU recurrence (encoder then decoder), poison-poll handoff.
// Blocks 64..255: GEMM workers (gi_enc, gi_dec concurrent with encoder;
// scores concurrent with decoder, polling hdec rows).
__global__ __launch_bounds__(1024, 1) void fused_kernel(
    const float* __restrict__ enc_whh, const float* __restrict__ enc_bhh,
    const float* __restrict__ dec_whh, const float* __restrict__ dec_bhh,
    const float* __restrict__ enc_state, const int* __restrict__ char_seq,
    const int* __restrict__ dec_in, const float* __restrict__ valid,
    const float* __restrict__ emb,
    const float* __restrict__ enc_wih, const float* __restrict__ enc_bih,
    const float* __restrict__ dec_wih, const float* __restrict__ dec_bih,
    const float* __restrict__ out_w, const float* __restrict__ out_b,
    float* gi_enc, float* gi_dec, float* hbuf, float* out_scores)
{
  __shared__ __align__(16) float As[4][16][132];
  __shared__ __align__(16) float Bs[4][16][132];
  __shared__ __align__(16) float hLDS[HID];
  __shared__ __align__(16) float ghPart[192];

  const int tid = threadIdx.x;

  if (blockIdx.x < NWG) {
    // ================= recurrence =================
    const int wg   = blockIdx.x;
    const int lane = tid & 63;
    const int w    = tid >> 6;

    if (tid < JB) publishf(&hbuf[wg * JB + tid], enc_state[wg * JB + tid]);
    if (tid >= 960 && tid < 976)            // warm rows 1..16 into IC
      atomicOr((unsigned int*)&hbuf[(size_t)(tid - 959) * HID + wg * JB], 0u);

    // weights: wave w owns rows rr=3w..3w+2 (rr = gate*16+jloc); lane holds k in [lane*16, lane*16+16)
    v2f wv[3][8];
#pragma unroll
    for (int r = 0; r < 3; r++) {
      int rr = w * 3 + r;
      const float* wrow = enc_whh + (size_t)((rr >> 4) * HID + wg * JB + (rr & 15)) * HID + lane * 16;
#pragma unroll
      for (int u = 0; u < 4; u++) {
        float4 t4 = *(const float4*)(wrow + u * 4);
        wv[r][2 * u]     = (v2f){t4.x, t4.y};
        wv[r][2 * u + 1] = (v2f){t4.z, t4.w};
      }
    }
    const int j = wg * JB + (tid & 15);
    float bhr = enc_bhh[j], bhz = enc_bhh[HID + j], bhn = enc_bhh[2 * HID + j];

    for (int s = 1; s <= 2 * SEQ_L; s++) {
      if (s == SEQ_L + 1) {
#pragma unroll
        for (int r = 0; r < 3; r++) {
          int rr = w * 3 + r;
          const float* wrow = dec_whh + (size_t)((rr >> 4) * HID + wg * JB + (rr & 15)) * HID + lane * 16;
#pragma unroll
          for (int u = 0; u < 4; u++) {
            float4 t4 = *(const float4*)(wrow + u * 4);
            wv[r][2 * u]     = (v2f){t4.x, t4.y};
            wv[r][2 * u + 1] = (v2f){t4.z, t4.w};
          }
        }
        bhr = dec_bhh[j]; bhz = dec_bhh[HID + j]; bhn = dec_bhh[2 * HID + j];
      }
      if (tid == 976 && s + 16 <= 2 * SEQ_L)
        atomicOr((unsigned int*)&hbuf[(size_t)(s + 16) * HID + wg * JB], 0u);

      // gi loads issued early (latency hidden under h poll); produced concurrently by workers
      float gir = 0.f, giz = 0.f, gin = 0.f;
      int cs = 1;
      const float* gi = (s <= SEQ_L) ? (gi_enc + (size_t)(s - 1) * G3)
                                     : (gi_dec + (size_t)(s - SEQ_L - 1) * G3);
      if (tid < JB) {
        gir = __hip_atomic_load((float*)&gi[j],           __ATOMIC_RELAXED, __HIP_MEMORY_SCOPE_AGENT);
        giz = __hip_atomic_load((float*)&gi[HID + j],     __ATOMIC_RELAXED, __HIP_MEMORY_SCOPE_AGENT);
        gin = __hip_atomic_load((float*)&gi[2 * HID + j], __ATOMIC_RELAXED, __HIP_MEMORY_SCOPE_AGENT);
        if (s <= SEQ_L) cs = char_seq[s - 1];
      }
      // poll own h dword
      const float* hp = hbuf + (size_t)(s - 1) * HID;
      float a = __hip_atomic_load((float*)&hp[tid], __ATOMIC_RELAXED, __HIP_MEMORY_SCOPE_AGENT);
      while (__float_as_uint(a) == POISON)
        a = __hip_atomic_load((float*)&hp[tid], __ATOMIC_RELAXED, __HIP_MEMORY_SCOPE_AGENT);
      // store into XOR-swizzled LDS (units of 4 floats; us = u ^ ((u>>3)&7))
      {
        int u0 = tid >> 2, us = u0 ^ ((u0 >> 3) & 7);
        hLDS[us * 4 + (tid & 3)] = a;
      }
      // fix gi stragglers (startup only)
      if (tid < JB) {
        while (__float_as_uint(gir) == POISON)
          gir = __hip_atomic_load((float*)&gi[j], __ATOMIC_RELAXED, __HIP_MEMORY_SCOPE_AGENT);
        while (__float_as_uint(giz) == POISON)
          giz = __hip_atomic_load((float*)&gi[HID + j], __ATOMIC_RELAXED, __HIP_MEMORY_SCOPE_AGENT);
        while (__float_as_uint(gin) == POISON)
          gin = __hip_atomic_load((float*)&gi[2 * HID + j], __ATOMIC_RELAXED, __HIP_MEMORY_SCOPE_AGENT);
      }
      __syncthreads();                       // barrier A: hLDS complete
      float hold = 0.f;
      if (tid < JB) {
        int uj = j >> 2, usj = uj ^ ((uj >> 3) & 7);
        hold = hLDS[usj * 4 + (j & 3)];
      }
      // 48 MACs/thread on b128 LDS fragments
      v2f acc2[3] = {(v2f){0.f, 0.f}, (v2f){0.f, 0.f}, (v2f){0.f, 0.f}};
#pragma unroll
      for (int u = 0; u < 4; u++) {
        int uu = lane * 4 + u, s2 = uu ^ ((uu >> 3) & 7);
        float4 hv = *(const float4*)&hLDS[s2 * 4];
        v2f h0 = (v2f){hv.x, hv.y}, h1 = (v2f){hv.z, hv.w};
#pragma unroll
        for (int r = 0; r < 3; r++) {
          acc2[r] = __builtin_elementwise_fma(wv[r][2 * u], h0, acc2[r]);
          acc2[r] = __builtin_elementwise_fma(wv[r][2 * u + 1], h1, acc2[r]);
        }
      }
      // DPP 16-lane reduce; lanes 0,16,32,48 write group partials
#pragma unroll
      for (int r = 0; r < 3; r++) {
        float t = row16_sum(acc2[r].x + acc2[r].y);
        if ((lane & 15) == 0) ghPart[(w * 3 + r) * 4 + (lane >> 4)] = t;
      }
      __syncthreads();                       // barrier B: partials complete
      if (tid < JB) {
        float4 p0 = *(const float4*)&ghPart[tid * 4];
        float4 p1 = *(const float4*)&ghPart[(16 + tid) * 4];
        float4 p2 = *(const float4*)&ghPart[(32 + tid) * 4];
        float ghr = (p0.x + p0.y) + (p0.z + p0.w) + bhr;
        float ghz = (p1.x + p1.y) + (p1.z + p1.w) + bhz;
        float ghn = (p2.x + p2.y) + (p2.z + p2.w) + bhn;
        float r = __builtin_amdgcn_rcpf(1.f + __expf(-(gir + ghr)));
        float z = __builtin_amdgcn_rcpf(1.f + __expf(-(giz + ghz)));
        float x = gin + r * ghn;
        float e = __expf(2.f * x);
        float n = 1.f - 2.f * __builtin_amdgcn_rcpf(e + 1.f);   // fast tanh
        float hnew = (1.f - z) * n + z * hold;
        if (s <= SEQ_L && cs == 0) hnew = hold;                 // encoder mask
        publishf(&hbuf[(size_t)s * HID + j], hnew);
      }
    }
  } else {
    // ================= GEMM workers =================
    const int wid  = blockIdx.x - NWG;
    const int sub  = tid >> 8;
    const int stid = tid & 255;
    float* hdec = hbuf + (size_t)(SEQ_L + 1) * HID;

    for (int item = wid; item < NITEM; item += NWORK) {
      if (item < 24) {            // gi_enc row-tile 0 as single tiles (fast startup)
        gemm_tile<0, 0>(emb, char_seq, enc_wih, enc_bih, nullptr, gi_enc,
                        G3, EMB, 0, item * 128, sub == 0, As[sub], Bs[sub], stid);
      } else if (item < 66) {     // gi_enc quads, row-tiles 1..7
        int qq = item - 24, rt = qq / 6 + 1, cq = qq % 6;
        gemm_tile<0, 0>(emb, char_seq, enc_wih, enc_bih, nullptr, gi_enc,
                        G3, EMB, rt * 128, (cq * 4 + sub) * 128, true, As[sub], Bs[sub], stid);
      } else if (item < 114) {    // gi_dec quads
        int qq = item - 66, rt = qq / 6, cq = qq % 6;
        gemm_tile<0, 0>(emb, dec_in, dec_wih, dec_bih, nullptr, gi_dec,
                        G3, EMB, rt * 128, (cq * 4 + sub) * 128, true, As[sub], Bs[sub], stid);
      } else if (item < 226) {    // score quads, row-tiles 0..6 (poll hdec)
        int qq = item - 114, rt = qq / 16, cq = qq % 16;
        gemm_tile<1, 1>(hdec, nullptr, out_w, out_b, valid, out_scores,
                        VOCAB, HID, rt * 128, (cq * 4 + sub) * 128, true, As[sub], Bs[sub], stid);
      } else {                    // score row-tile 7 as single tiles (short tail)
        int col = item - 226;
        gemm_tile<1, 1>(hdec, nullptr, out_w, out_b, valid, out_scores,
                        VOCAB, HID, 7 * 128, col * 128, sub == 0, As[sub], Bs[sub], stid);
      }
    }
  }
}

// ---------------- states output: hdec * valid ----------------
__global__ __launch_bounds__(256) void states_kernel(
    const float* __restrict__ hdec, const float* __restrict__ valid,
    float* __restrict__ out2)
{
  int i = blockIdx.x * 256 + threadIdx.x;
  out2[i] = hdec[i] * valid[i >> 10];
}

extern "C" void kernel_launch(void* const* d_in, const int* in_sizes, int n_in,
                              void* d_out, int out_size, void* d_ws, size_t ws_size,
                              hipStream_t stream)
{
  const int*   char_seq  = (const int*)  d_in[0];
  const int*   target    = (const int*)  d_in[1];
  const float* enc_state = (const float*)d_in[2];
  const float* emb       = (const float*)d_in[3];
  const float* enc_wih   = (const float*)d_in[4];
  const float* enc_whh   = (const float*)d_in[5];
  const float* enc_bih   = (const float*)d_in[6];
  const float* enc_bhh   = (const float*)d_in[7];
  const float* dec_wih   = (const float*)d_in[8];
  const float* dec_whh   = (const float*)d_in[9];
  const float* dec_bih   = (const float*)d_in[10];
  const float* dec_bhh   = (const float*)d_in[11];
  const float* out_w     = (const float*)d_in[12];
  const float* out_b     = (const float*)d_in[13];
  const int*   sos_p     = (const int*)  d_in[14];
  const int*   eos_p     = (const int*)  d_in[15];

  char* ws = (char*)d_ws;
  float* gi_enc = (float*)ws;  ws += (size_t)SEQ_L * G3 * sizeof(float);
  float* gi_dec = (float*)ws;  ws += (size_t)SEQ_L * G3 * sizeof(float);
  float* hbuf   = (float*)ws;  ws += (size_t)(2 * SEQ_L + 1) * HID * sizeof(float);
  float* valid  = (float*)ws;  ws += SEQ_L * sizeof(float);
  int*   dec_in = (int*)ws;    ws += SEQ_L * sizeof(int);

  float* hdec = hbuf + (size_t)(SEQ_L + 1) * HID;
  float* out_scores = (float*)d_out;
  float* out_states = out_scores + (size_t)SEQ_L * VOCAB;

  prep_kernel<<<1, 1024, 0, stream>>>(target, sos_p, eos_p, dec_in, valid);
  fused_kernel<<<NWG + NWORK, 1024, 0, stream>>>(
      enc_whh, enc_bhh, dec_whh, dec_bhh, enc_state, char_seq,
      dec_in, valid, emb, enc_wih, enc_bih, dec_wih, dec_bih,
      out_w, out_b, gi_enc, gi_dec, hbuf, out_scores);
  states_kernel<<<(SEQ_L * HID) / 256, 256, 0, stream>>>(hdec, valid, out_states);
}